// Round 8
// baseline (209.758 us; speedup 1.0000x reference)
//
#include <hip/hip_runtime.h>
#include <hip/hip_bf16.h>

// Problem constants (setup_inputs is fixed)
#define S_LEN 2048
#define BATCH 2
#define EMB   1024
#define NHEAD 16
#define HDIM  64
#define WIN   128

typedef __attribute__((ext_vector_type(8))) short short8;
typedef __attribute__((ext_vector_type(4))) float floatx4;

// Pack two f32 into two RNE-rounded bf16 (lo = a, hi = b).
__device__ __forceinline__ unsigned int pk2bf(float a, float b) {
    unsigned int ua = __builtin_bit_cast(unsigned int, a);
    unsigned int ub = __builtin_bit_cast(unsigned int, b);
    ua += 0x7fffu + ((ua >> 16) & 1u);
    ub += 0x7fffu + ((ub >> 16) & 1u);
    return (ua >> 16) | (ub & 0xffff0000u);
}
__device__ __forceinline__ unsigned short f2bf(float f) {
    unsigned int u = __builtin_bit_cast(unsigned int, f);
    u += 0x7fffu + ((u >> 16) & 1u);
    return (unsigned short)(u >> 16);
}

// Async global->LDS, 16 B per lane. LDS dest = wave-uniform base + lane*16.
__device__ __forceinline__ void gl_lds16(const unsigned short* g, unsigned short* l) {
    __builtin_amdgcn_global_load_lds(
        (const __attribute__((address_space(1))) unsigned int*)g,
        (__attribute__((address_space(3))) unsigned int*)l,
        16, 0, 0);
}

// ---------------------------------------------------------------------------
// Convert pass: f32 -> bf16 for x(q,k,v), in_proj_w, out_proj_w.
// (r4 form — fusing x-convert into qkv measured −26 µs regression, reverted.)
// ---------------------------------------------------------------------------
#define QKV_UNITS 524288          // 4194304/8
#define WI_UNITS  393216          // 3145728/8
#define WO_UNITS  131072          // 1048576/8

__global__ __launch_bounds__(256)
void convert_kernel(const float* __restrict__ xq, const float* __restrict__ xk,
                    const float* __restrict__ xv, const float* __restrict__ wi,
                    const float* __restrict__ wo,
                    unsigned short* __restrict__ xqb, unsigned short* __restrict__ xkb,
                    unsigned short* __restrict__ xvb, unsigned short* __restrict__ wib,
                    unsigned short* __restrict__ wob)
{
    const size_t u = (size_t)blockIdx.x * 256 + threadIdx.x;
    const float* src;
    unsigned short* dst;
    size_t off;
    if (u < 3 * (size_t)QKV_UNITS) {
        const int which = (int)(u / QKV_UNITS);
        off = (u % QKV_UNITS) * 8;
        src = (which == 0) ? xq : (which == 1) ? xk : xv;
        dst = (which == 0) ? xqb : (which == 1) ? xkb : xvb;
    } else if (u < 3 * (size_t)QKV_UNITS + WI_UNITS) {
        off = (u - 3 * (size_t)QKV_UNITS) * 8;
        src = wi; dst = wib;
    } else {
        off = (u - (3 * (size_t)QKV_UNITS + WI_UNITS)) * 8;
        src = wo; dst = wob;
    }
    float4 a = *reinterpret_cast<const float4*>(src + off);
    float4 b = *reinterpret_cast<const float4*>(src + off + 4);
    uint4 p = {pk2bf(a.x, a.y), pk2bf(a.z, a.w), pk2bf(b.x, b.y), pk2bf(b.z, b.w)};
    *reinterpret_cast<uint4*>(dst + off) = p;
}

// ---------------------------------------------------------------------------
// QKV projection, bf16 MFMA GEMM. 128x64 tiles -> grid 1536 (6 blocks/CU,
// was 3): inter-block overlap of the staging drains (same lever that won in
// out_gemm r3->r4). BK=32, 12 KB LDS, 2 barriers/K-step, 4-way XOR swizzle,
// per-wave 32x64 sub-tile (acc[2][4]). XCD key = by, so all 16 col-tiles
// sharing an A-panel land on one XCD (L2-served re-read).
// Outputs bf16: q,k as [B,H,S,D] (q scaled 0.125), v transposed [B,H,D,S]
// via direct scatter stores (bounce variants all measured slower).
// ---------------------------------------------------------------------------
__global__ __launch_bounds__(256)
void qkv_gemm_kernel(const unsigned short* __restrict__ xqb,
                     const unsigned short* __restrict__ xkb,
                     const unsigned short* __restrict__ xvb,
                     const unsigned short* __restrict__ wib,   // [3E, E] bf16
                     const float* __restrict__ bias,           // [3E] f32
                     unsigned short* __restrict__ qo,
                     unsigned short* __restrict__ ko,
                     unsigned short* __restrict__ vto)
{
    __shared__ unsigned short As[128 * 32];   // 8 KB
    __shared__ unsigned short Bs[64 * 32];    // 4 KB

    const int bid  = blockIdx.x;
    const int which = bid >> 9;            // 0..2 (512 blocks each)
    const int bx   = (bid >> 5) & 15;      // col-tile (64 cols)
    const int by   = bid & 31;             // row-panel (128 rows, XCD key)

    const unsigned short* A = (which == 0) ? xqb : (which == 1) ? xkb : xvb;
    const unsigned short* W = wib + (size_t)which * EMB * EMB;
    const float* bv = bias + which * EMB;
    const float scale = (which == 0) ? 0.125f : 1.0f;

    const int tid  = threadIdx.x;
    const int lane = tid & 63;
    const int wave = tid >> 6;
    const int quad = lane >> 4;
    const int c16  = lane & 15;
    const int wm   = wave * 32;            // wave owns 32 rows x 64 cols

    const int rowBase = by * 128;
    const int colBase = bx * 64;

    // Staging: chunk c = 16 rows x 32 ushorts; lane -> (lrow, XOR-perm seg).
    const int lrow = lane >> 2;                        // 0..15 within chunk
    const int lseg = (((lane & 3) ^ (lrow & 3)) << 3); // permuted k-seg (ushorts)

    floatx4 acc[2][4];
    #pragma unroll
    for (int i = 0; i < 2; ++i)
        #pragma unroll
        for (int j = 0; j < 4; ++j)
            acc[i][j] = (floatx4){0.f, 0.f, 0.f, 0.f};

    const int rxor = c16 & 3;   // read-side XOR key (row&3 == c16&3)

    for (int k0 = 0; k0 < EMB; k0 += 32) {
        __syncthreads();
        #pragma unroll
        for (int t = 0; t < 2; ++t) {              // A: 8 chunks of 16 rows
            const int c = wave * 2 + t;
            const int row = c * 16 + lrow;
            gl_lds16(A + (size_t)(rowBase + row) * EMB + k0 + lseg, &As[c * 512]);
        }
        {                                           // B: 4 chunks of 16 rows
            const int row = wave * 16 + lrow;
            gl_lds16(W + (size_t)(colBase + row) * EMB + k0 + lseg, &Bs[wave * 512]);
        }
        __syncthreads();

        const int soff = ((quad ^ rxor) << 3);
        short8 af[2], bf[4];
        #pragma unroll
        for (int mi = 0; mi < 2; ++mi)
            af[mi] = *reinterpret_cast<const short8*>(
                &As[(wm + mi * 16 + c16) * 32 + soff]);
        #pragma unroll
        for (int ni = 0; ni < 4; ++ni)
            bf[ni] = *reinterpret_cast<const short8*>(
                &Bs[(ni * 16 + c16) * 32 + soff]);

        #pragma unroll
        for (int mi = 0; mi < 2; ++mi)
            #pragma unroll
            for (int ni = 0; ni < 4; ++ni)
                acc[mi][ni] = __builtin_amdgcn_mfma_f32_16x16x32_bf16(
                    af[mi], bf[ni], acc[mi][ni], 0, 0, 0);
    }

    // Epilogue -> bf16. D[m = quad*4+r][n = c16] per 16x16 tile (scatter).
    #pragma unroll
    for (int ni = 0; ni < 4; ++ni) {
        const int n_full = colBase + ni * 16 + c16;        // 0..1023
        const float bb = bv[n_full];
        const int h = n_full >> 6;
        const int d = n_full & 63;
        #pragma unroll
        for (int mi = 0; mi < 2; ++mi) {
            #pragma unroll
            for (int r = 0; r < 4; ++r) {
                const int m_g = rowBase + wm + mi * 16 + quad * 4 + r;
                const int s   = m_g >> 1;      // m = s*B + b
                const int b   = m_g & 1;
                const int bh  = b * NHEAD + h;
                const unsigned short val = f2bf((acc[mi][ni][r] + bb) * scale);
                if (which == 2)
                    vto[((size_t)bh * HDIM + d) * S_LEN + s] = val;
                else if (which == 0)
                    qo[((size_t)bh * S_LEN + s) * HDIM + d] = val;
                else
                    ko[((size_t)bh * S_LEN + s) * HDIM + d] = val;
            }
        }
    }
}

// ---------------------------------------------------------------------------
// MFMA flash attention over the band (r4 proven form, verbatim).
// 1D grid, XCD-swizzled (bid = sx*32+bh). Swapped QK^T (mfma(K,Q)): lane
// holds the full P-row for q=c16, softmax lane-local. s_setprio(1) around
// MFMA clusters. K/V reg-prefetched one block ahead. ctx out bf16.
// ---------------------------------------------------------------------------
#define AT_STRIDE 72   // ushorts per LDS row (144B)

__global__ __launch_bounds__(256)
void attn_mfma_kernel(const unsigned short* __restrict__ q,
                      const unsigned short* __restrict__ k,
                      const unsigned short* __restrict__ vt,
                      unsigned short* __restrict__ ctx)
{
    __shared__ unsigned short Qs[64 * AT_STRIDE];
    __shared__ unsigned short Ks[64 * AT_STRIDE];
    __shared__ unsigned short Vts[64 * AT_STRIDE];
    __shared__ unsigned short Ps[64 * AT_STRIDE];

    const int bid = blockIdx.x;
    const int bh  = bid & 31;
    const int s0  = (bid >> 5) * 64;
    const int tid = threadIdx.x;
    const int lane = tid & 63;
    const int wave = tid >> 6;
    const int quad = lane >> 4;
    const int c16  = lane & 15;

    const size_t base_qk = ((size_t)bh * S_LEN) * HDIM;
    const size_t base_vt = ((size_t)bh * HDIM) * S_LEN;

    const int srow = tid >> 2;
    const int sseg = (tid & 3) << 4;
    {
        const unsigned short* src = q + base_qk + (size_t)(s0 + srow) * HDIM + sseg;
        uint4 v0 = *reinterpret_cast<const uint4*>(src);
        uint4 v1 = *reinterpret_cast<const uint4*>(src + 8);
        *reinterpret_cast<uint4*>(&Qs[srow * AT_STRIDE + sseg])     = v0;
        *reinterpret_cast<uint4*>(&Qs[srow * AT_STRIDE + sseg + 8]) = v1;
    }

    // Per-lane softmax state for q-row = s0 + wave*16 + c16 (uniform over quad).
    float m_ = -1.0e30f, l_ = 0.f;
    floatx4 ob[4];
    #pragma unroll
    for (int dt = 0; dt < 4; ++dt) ob[dt] = (floatx4){0.f, 0.f, 0.f, 0.f};

    const int qg = s0 + wave * 16 + c16;   // this lane's q row

    int c0 = s0 - 128; if (c0 < 0) c0 = 0;
    int c1 = s0 + 192; if (c1 > S_LEN) c1 = S_LEN;

    uint4 k0v, k1v, v0v, v1v;
#define LOADKV(CB)                                                                \
    {                                                                             \
        const unsigned short* ksrc = k + base_qk + (size_t)((CB) + srow) * HDIM + sseg; \
        const unsigned short* vsrc = vt + base_vt + (size_t)srow * S_LEN + (CB) + sseg; \
        k0v = *reinterpret_cast<const uint4*>(ksrc);                              \
        k1v = *reinterpret_cast<const uint4*>(ksrc + 8);                          \
        v0v = *reinterpret_cast<const uint4*>(vsrc);                              \
        v1v = *reinterpret_cast<const uint4*>(vsrc + 8);                          \
    }

    LOADKV(c0);

    for (int cb = c0; cb < c1; cb += 64) {
        __syncthreads();      // previous tile's readers done
        *reinterpret_cast<uint4*>(&Ks[srow * AT_STRIDE + sseg])      = k0v;
        *reinterpret_cast<uint4*>(&Ks[srow * AT_STRIDE + sseg + 8])  = k1v;
        *reinterpret_cast<uint4*>(&Vts[srow * AT_STRIDE + sseg])     = v0v;
        *reinterpret_cast<uint4*>(&Vts[srow * AT_STRIDE + sseg + 8]) = v1v;
        __syncthreads();      // K/V tile visible
        if (cb + 64 < c1) LOADKV(cb + 64);   // prefetch next (hides under compute)

        // Swapped QK^T: sc[jt] = K_tile(jt) x Q -> lane holds
        // S[q = qg][j = cb + jt*16 + quad*4 + r], r = 0..3.
        floatx4 sc[4];
        #pragma unroll
        for (int jt = 0; jt < 4; ++jt) sc[jt] = (floatx4){0.f, 0.f, 0.f, 0.f};
        {
            short8 af0 = *reinterpret_cast<const short8*>(
                &Qs[(wave * 16 + c16) * AT_STRIDE + quad * 8]);
            short8 af1 = *reinterpret_cast<const short8*>(
                &Qs[(wave * 16 + c16) * AT_STRIDE + 32 + quad * 8]);
            __builtin_amdgcn_s_setprio(1);
            #pragma unroll
            for (int jt = 0; jt < 4; ++jt) {
                short8 bf0 = *reinterpret_cast<const short8*>(
                    &Ks[(jt * 16 + c16) * AT_STRIDE + quad * 8]);
                short8 bf1 = *reinterpret_cast<const short8*>(
                    &Ks[(jt * 16 + c16) * AT_STRIDE + 32 + quad * 8]);
                sc[jt] = __builtin_amdgcn_mfma_f32_16x16x32_bf16(bf0, af0, sc[jt], 0, 0, 0);
                sc[jt] = __builtin_amdgcn_mfma_f32_16x16x32_bf16(bf1, af1, sc[jt], 0, 0, 0);
            }
            __builtin_amdgcn_s_setprio(0);
        }

        // Lane-local online softmax over the 16 values of this lane's row.
        float rm = -3.0e38f;
        #pragma unroll
        for (int jt = 0; jt < 4; ++jt) {
            #pragma unroll
            for (int r = 0; r < 4; ++r) {
                const int jg = cb + jt * 16 + quad * 4 + r;
                float x = sc[jt][r];
                if (jg < qg - WIN || jg >= qg + WIN) x = -3.0e38f;
                sc[jt][r] = x;
                rm = fmaxf(rm, x);
            }
        }
        rm = fmaxf(rm, __shfl_xor(rm, 16));
        rm = fmaxf(rm, __shfl_xor(rm, 32));
        const float mn    = fmaxf(m_, rm);
        const float alpha = __expf(m_ - mn);
        float rs = 0.f;
        #pragma unroll
        for (int jt = 0; jt < 4; ++jt) {
            #pragma unroll
            for (int r = 0; r < 4; ++r) {
                const float p = __expf(sc[jt][r] - mn);
                sc[jt][r] = p;
                rs += p;
            }
        }
        rs += __shfl_xor(rs, 16);
        rs += __shfl_xor(rs, 32);
        l_ = l_ * alpha + rs;
        m_ = mn;

        // Broadcast alpha to PV accumulator rows (q = wave*16 + quad*4 + r).
        #pragma unroll
        for (int r = 0; r < 4; ++r) {
            const float ar = __shfl(alpha, (lane & 48) | (quad * 4 + r));
            #pragma unroll
            for (int dt = 0; dt < 4; ++dt) ob[dt][r] *= ar;
        }

        // Packed P-store: lane writes its row q=c16, j = jt*16 + quad*4 + 0..3.
        #pragma unroll
        for (int jt = 0; jt < 4; ++jt) {
            uint2 pw;
            pw.x = pk2bf(sc[jt][0], sc[jt][1]);
            pw.y = pk2bf(sc[jt][2], sc[jt][3]);
            *reinterpret_cast<uint2*>(
                &Ps[(wave * 16 + c16) * AT_STRIDE + jt * 16 + quad * 4]) = pw;
        }

        {
            short8 pa0 = *reinterpret_cast<const short8*>(
                &Ps[(wave * 16 + c16) * AT_STRIDE + quad * 8]);
            short8 pa1 = *reinterpret_cast<const short8*>(
                &Ps[(wave * 16 + c16) * AT_STRIDE + 32 + quad * 8]);
            __builtin_amdgcn_s_setprio(1);
            #pragma unroll
            for (int dt = 0; dt < 4; ++dt) {
                short8 bv0 = *reinterpret_cast<const short8*>(
                    &Vts[(dt * 16 + c16) * AT_STRIDE + quad * 8]);
                short8 bv1 = *reinterpret_cast<const short8*>(
                    &Vts[(dt * 16 + c16) * AT_STRIDE + 32 + quad * 8]);
                ob[dt] = __builtin_amdgcn_mfma_f32_16x16x32_bf16(pa0, bv0, ob[dt], 0, 0, 0);
                ob[dt] = __builtin_amdgcn_mfma_f32_16x16x32_bf16(pa1, bv1, ob[dt], 0, 0, 0);
            }
            __builtin_amdgcn_s_setprio(0);
        }
    }
#undef LOADKV

    // Epilogue: O/l -> ctx [S,B,E] bf16 (inv broadcast from softmax lanes).
    const int b = bh >> 4;
    const int h = bh & 15;
    #pragma unroll
    for (int r = 0; r < 4; ++r) {
        const int sg  = s0 + wave * 16 + quad * 4 + r;
        const float lr = __shfl(l_, (lane & 48) | (quad * 4 + r));
        const float inv = 1.0f / lr;
        #pragma unroll
        for (int dt = 0; dt < 4; ++dt) {
            const int d = dt * 16 + c16;
            ctx[((size_t)(sg * BATCH + b) << 10) + (h << 6) + d] = f2bf(ob[dt][r] * inv);
        }
    }
}

// ---------------------------------------------------------------------------
// Output projection (r4 proven form, verbatim). 128x64 tiles -> grid 512
// (2 blocks/CU), BK=64 + 8-way XOR swizzle, 2-barrier single-buffer.
// ctx: [4096,1024] bf16, W: [1024,1024] bf16, out: [S,B,E] f32.
// ---------------------------------------------------------------------------
__global__ __launch_bounds__(256)
void out_gemm_kernel(const unsigned short* __restrict__ ctxb,
                     const unsigned short* __restrict__ wob,
                     const float* __restrict__ bias,
                     float* __restrict__ out)
{
    __shared__ unsigned short As[128 * 64];   // 16 KB
    __shared__ unsigned short Bs[64 * 64];    //  8 KB

    const int bid = blockIdx.x;
    const int bx  = bid >> 5;        // col-tile 0..15 (64 cols)
    const int by  = bid & 31;        // row-panel 0..31 (128 rows, XCD key)

    const int tid  = threadIdx.x;
    const int lane = tid & 63;
    const int wave = tid >> 6;
    const int quad = lane >> 4;
    const int c16  = lane & 15;
    const int wm   = wave * 32;      // wave owns 32 rows x 64 cols

    const int rowBase = by * 128;
    const int colBase = bx * 64;

    const int lrow = lane >> 3;                    // 0..7 within chunk
    const int lseg = (((lane & 7) ^ lrow) << 3);   // permuted k-seg (ushorts)

    floatx4 acc[2][4];
    #pragma unroll
    for (int i = 0; i < 2; ++i)
        #pragma unroll
        for (int j = 0; j < 4; ++j)
            acc[i][j] = (floatx4){0.f, 0.f, 0.f, 0.f};

    const int rxor = c16 & 7;

    for (int k0 = 0; k0 < EMB; k0 += 64) {
        __syncthreads();
        #pragma unroll
        for (int t = 0; t < 4; ++t) {            // A: 16 chunks of 8 rows
            const int c = wave * 4 + t;
            const int row = c * 8 + lrow;
            gl_lds16(ctxb + (size_t)(rowBase + row) * EMB + k0 + lseg, &As[c * 512]);
        }
        #pragma unroll
        for (int t = 0; t < 2; ++t) {            // B: 8 chunks of 8 rows
            const int c = wave * 2 + t;
            const int row = c * 8 + lrow;
            gl_lds16(wob + (size_t)(colBase + row) * EMB + k0 + lseg, &Bs[c * 512]);
        }
        __syncthreads();

        #pragma unroll
        for (int kk = 0; kk < 2; ++kk) {
            const int soff = (((quad + 4 * kk) ^ rxor) << 3);
            short8 af[2], bf[4];
            #pragma unroll
            for (int mi = 0; mi < 2; ++mi)
                af[mi] = *reinterpret_cast<const short8*>(
                    &As[(wm + mi * 16 + c16) * 64 + soff]);
            #pragma unroll
            for (int ni = 0; ni < 4; ++ni)
                bf[ni] = *reinterpret_cast<const short8*>(
                    &Bs[(ni * 16 + c16) * 64 + soff]);

            #pragma unroll
            for (int mi = 0; mi < 2; ++mi)
                #pragma unroll
                for (int ni = 0; ni < 4; ++ni)
                    acc[mi][ni] = __builtin_amdgcn_mfma_f32_16x16x32_bf16(
                        af[mi], bf[ni], acc[mi][ni], 0, 0, 0);
        }
    }

    #pragma unroll
    for (int ni = 0; ni < 4; ++ni) {
        const int n_full = colBase + ni * 16 + c16;
        const float bb = bias[n_full];
        #pragma unroll
        for (int mi = 0; mi < 2; ++mi) {
            #pragma unroll
            for (int r = 0; r < 4; ++r) {
                const int m_g = rowBase + wm + mi * 16 + quad * 4 + r;
                out[(size_t)m_g * EMB + n_full] = acc[mi][ni][r] + bb;
            }
        }
    }
}

// ---------------------------------------------------------------------------
extern "C" void kernel_launch(void* const* d_in, const int* in_sizes, int n_in,
                              void* d_out, int out_size, void* d_ws, size_t ws_size,
                              hipStream_t stream) {
    const float* query = (const float*)d_in[0];
    const float* key   = (const float*)d_in[1];
    const float* value = (const float*)d_in[2];
    const float* in_w  = (const float*)d_in[3];
    const float* in_b  = (const float*)d_in[4];
    const float* out_w = (const float*)d_in[5];
    const float* out_b = (const float*)d_in[6];

    const size_t PLANE = (size_t)BATCH * NHEAD * S_LEN * HDIM;  // 4194304
    unsigned short* xqb = (unsigned short*)d_ws;
    unsigned short* xkb = xqb + PLANE;
    unsigned short* xvb = xkb + PLANE;
    unsigned short* wib = xvb + PLANE;                 // 3*EMB*EMB
    unsigned short* wob = wib + (size_t)3 * EMB * EMB; // EMB*EMB
    unsigned short* qo  = wob + (size_t)EMB * EMB;
    unsigned short* ko  = qo + PLANE;
    unsigned short* vto = ko + PLANE;
    unsigned short* cw  = vto + PLANE;

    convert_kernel<<<8192, 256, 0, stream>>>(query, key, value, in_w, out_w,
                                             xqb, xkb, xvb, wib, wob);

    qkv_gemm_kernel<<<1536, 256, 0, stream>>>(xqb, xkb, xvb, wib, in_b, qo, ko, vto);

    attn_mfma_kernel<<<1024, 256, 0, stream>>>(qo, ko, vto, cw);

    out_gemm_kernel<<<512, 256, 0, stream>>>(cw, wob, out_b, (float*)d_out);
}

// Round 9
// 189.210 us; speedup vs baseline: 1.1086x; 1.1086x over previous
//
#include <hip/hip_runtime.h>
#include <hip/hip_bf16.h>

// Problem constants (setup_inputs is fixed)
#define S_LEN 2048
#define BATCH 2
#define EMB   1024
#define NHEAD 16
#define HDIM  64
#define WIN   128

typedef __attribute__((ext_vector_type(8))) short short8;
typedef __attribute__((ext_vector_type(4))) float floatx4;

// Pack two f32 into two RNE-rounded bf16 (lo = a, hi = b).
__device__ __forceinline__ unsigned int pk2bf(float a, float b) {
    unsigned int ua = __builtin_bit_cast(unsigned int, a);
    unsigned int ub = __builtin_bit_cast(unsigned int, b);
    ua += 0x7fffu + ((ua >> 16) & 1u);
    ub += 0x7fffu + ((ub >> 16) & 1u);
    return (ua >> 16) | (ub & 0xffff0000u);
}
__device__ __forceinline__ unsigned short f2bf(float f) {
    unsigned int u = __builtin_bit_cast(unsigned int, f);
    u += 0x7fffu + ((u >> 16) & 1u);
    return (unsigned short)(u >> 16);
}

// Async global->LDS, 16 B per lane. LDS dest = wave-uniform base + lane*16.
__device__ __forceinline__ void gl_lds16(const unsigned short* g, unsigned short* l) {
    __builtin_amdgcn_global_load_lds(
        (const __attribute__((address_space(1))) unsigned int*)g,
        (__attribute__((address_space(3))) unsigned int*)l,
        16, 0, 0);
}

// ---------------------------------------------------------------------------
// Convert pass: f32 -> bf16 for x(q,k,v), in_proj_w, out_proj_w.
// ---------------------------------------------------------------------------
#define QKV_UNITS 524288          // 4194304/8
#define WI_UNITS  393216          // 3145728/8
#define WO_UNITS  131072          // 1048576/8

__global__ __launch_bounds__(256)
void convert_kernel(const float* __restrict__ xq, const float* __restrict__ xk,
                    const float* __restrict__ xv, const float* __restrict__ wi,
                    const float* __restrict__ wo,
                    unsigned short* __restrict__ xqb, unsigned short* __restrict__ xkb,
                    unsigned short* __restrict__ xvb, unsigned short* __restrict__ wib,
                    unsigned short* __restrict__ wob)
{
    const size_t u = (size_t)blockIdx.x * 256 + threadIdx.x;
    const float* src;
    unsigned short* dst;
    size_t off;
    if (u < 3 * (size_t)QKV_UNITS) {
        const int which = (int)(u / QKV_UNITS);
        off = (u % QKV_UNITS) * 8;
        src = (which == 0) ? xq : (which == 1) ? xk : xv;
        dst = (which == 0) ? xqb : (which == 1) ? xkb : xvb;
    } else if (u < 3 * (size_t)QKV_UNITS + WI_UNITS) {
        off = (u - 3 * (size_t)QKV_UNITS) * 8;
        src = wi; dst = wib;
    } else {
        off = (u - (3 * (size_t)QKV_UNITS + WI_UNITS)) * 8;
        src = wo; dst = wob;
    }
    float4 a = *reinterpret_cast<const float4*>(src + off);
    float4 b = *reinterpret_cast<const float4*>(src + off + 4);
    uint4 p = {pk2bf(a.x, a.y), pk2bf(a.z, a.w), pk2bf(b.x, b.y), pk2bf(b.z, b.w)};
    *reinterpret_cast<uint4*>(dst + off) = p;
}

// ---------------------------------------------------------------------------
// QKV projection, bf16 MFMA GEMM. r4 proven form, verbatim (do NOT perturb:
// dbuf 58.4, BK64+bounce 49.1, BK32+bounce 53.5, BK64+scatter 61.8, fused
// convert 71, 128x64 tile 66 — all measured worse than this 45.5 µs form):
// 128x128 tile, BK=32 (16 KB LDS), 2 barriers/K-step, XCD-swizzled 1D grid.
// global_load_lds staging with XOR-swizzled 16B k-segments (4-way).
// Outputs bf16: q,k as [B,H,S,D] (q scaled 0.125), v transposed [B,H,D,S]
// via direct scatter stores.
// ---------------------------------------------------------------------------
__global__ __launch_bounds__(256)
void qkv_gemm_kernel(const unsigned short* __restrict__ xqb,
                     const unsigned short* __restrict__ xkb,
                     const unsigned short* __restrict__ xvb,
                     const unsigned short* __restrict__ wib,   // [3E, E] bf16
                     const float* __restrict__ bias,           // [3E] f32
                     unsigned short* __restrict__ qo,
                     unsigned short* __restrict__ ko,
                     unsigned short* __restrict__ vto)
{
    __shared__ unsigned short As[128 * 32];
    __shared__ unsigned short Bs[128 * 32];

    const int bid  = blockIdx.x;
    const int which = bid >> 8;            // z
    const int bx   = (bid >> 5) & 7;       // col-tile
    const int by   = bid & 31;             // row-panel (XCD key)

    const unsigned short* A = (which == 0) ? xqb : (which == 1) ? xkb : xvb;
    const unsigned short* W = wib + (size_t)which * EMB * EMB;
    const float* bv = bias + which * EMB;
    const float scale = (which == 0) ? 0.125f : 1.0f;

    const int tid  = threadIdx.x;
    const int lane = tid & 63;
    const int wave = tid >> 6;
    const int quad = lane >> 4;
    const int c16  = lane & 15;
    const int wm   = (wave & 1) << 6;
    const int wn   = (wave >> 1) << 6;

    const int rowBase = by * 128;
    const int colBase = bx * 128;

    // Staging: chunk c = 16 rows x 32 ushorts; lane -> (lrow, XOR-perm seg).
    const int lrow = lane >> 2;                        // 0..15 within chunk
    const int lseg = (((lane & 3) ^ (lrow & 3)) << 3); // permuted k-seg (ushorts)

    floatx4 acc[4][4];
    #pragma unroll
    for (int i = 0; i < 4; ++i)
        #pragma unroll
        for (int j = 0; j < 4; ++j)
            acc[i][j] = (floatx4){0.f, 0.f, 0.f, 0.f};

    const int rxor = c16 & 3;   // read-side XOR key (row&3 == c16&3)

    for (int k0 = 0; k0 < EMB; k0 += 32) {
        __syncthreads();
        #pragma unroll
        for (int t = 0; t < 2; ++t) {
            const int c = wave * 2 + t;
            const int row = c * 16 + lrow;
            gl_lds16(A + (size_t)(rowBase + row) * EMB + k0 + lseg, &As[c * 512]);
            gl_lds16(W + (size_t)(colBase + row) * EMB + k0 + lseg, &Bs[c * 512]);
        }
        __syncthreads();

        const int soff = ((quad ^ rxor) << 3);
        short8 af[4], bf[4];
        #pragma unroll
        for (int mi = 0; mi < 4; ++mi)
            af[mi] = *reinterpret_cast<const short8*>(
                &As[(wm + mi * 16 + c16) * 32 + soff]);
        #pragma unroll
        for (int ni = 0; ni < 4; ++ni)
            bf[ni] = *reinterpret_cast<const short8*>(
                &Bs[(wn + ni * 16 + c16) * 32 + soff]);

        #pragma unroll
        for (int mi = 0; mi < 4; ++mi)
            #pragma unroll
            for (int ni = 0; ni < 4; ++ni)
                acc[mi][ni] = __builtin_amdgcn_mfma_f32_16x16x32_bf16(
                    af[mi], bf[ni], acc[mi][ni], 0, 0, 0);
    }

    // Epilogue -> bf16. D[m = quad*4+r][n = c16] per 16x16 tile.
    #pragma unroll
    for (int ni = 0; ni < 4; ++ni) {
        const int n_full = colBase + wn + ni * 16 + c16;   // 0..1023
        const float bb = bv[n_full];
        const int h = n_full >> 6;
        const int d = n_full & 63;
        #pragma unroll
        for (int mi = 0; mi < 4; ++mi) {
            #pragma unroll
            for (int r = 0; r < 4; ++r) {
                const int m_g = rowBase + wm + mi * 16 + quad * 4 + r;
                const int s   = m_g >> 1;      // m = s*B + b
                const int b   = m_g & 1;
                const int bh  = b * NHEAD + h;
                const unsigned short val = f2bf((acc[mi][ni][r] + bb) * scale);
                if (which == 2)
                    vto[((size_t)bh * HDIM + d) * S_LEN + s] = val;
                else if (which == 0)
                    qo[((size_t)bh * S_LEN + s) * HDIM + d] = val;
                else
                    ko[((size_t)bh * S_LEN + s) * HDIM + d] = val;
            }
        }
    }
}

// ---------------------------------------------------------------------------
// MFMA flash attention over the band. 1D grid, XCD-swizzled (bid = sx*32+bh).
// Swapped QK^T (mfma(K,Q)): lane holds the full P-row for q=c16, softmax is
// lane-local (4 shfl_xor total, scalar m/l, packed b64 P-stores).
// T13 defer-max (THR=8): skip the O-rescale when no row's tile-max exceeds
// the running max by >8 (P bounded by e^8; bf16-safe). alpha==exp(0)==1
// exactly on the skip path, so l_ update stays exact.
// s_setprio(1) around MFMA clusters. K/V reg-prefetched one block ahead.
// ---------------------------------------------------------------------------
#define AT_STRIDE 72   // ushorts per LDS row (144B)

__global__ __launch_bounds__(256)
void attn_mfma_kernel(const unsigned short* __restrict__ q,
                      const unsigned short* __restrict__ k,
                      const unsigned short* __restrict__ vt,
                      unsigned short* __restrict__ ctx)
{
    __shared__ unsigned short Qs[64 * AT_STRIDE];
    __shared__ unsigned short Ks[64 * AT_STRIDE];
    __shared__ unsigned short Vts[64 * AT_STRIDE];
    __shared__ unsigned short Ps[64 * AT_STRIDE];

    const int bid = blockIdx.x;
    const int bh  = bid & 31;
    const int s0  = (bid >> 5) * 64;
    const int tid = threadIdx.x;
    const int lane = tid & 63;
    const int wave = tid >> 6;
    const int quad = lane >> 4;
    const int c16  = lane & 15;

    const size_t base_qk = ((size_t)bh * S_LEN) * HDIM;
    const size_t base_vt = ((size_t)bh * HDIM) * S_LEN;

    const int srow = tid >> 2;
    const int sseg = (tid & 3) << 4;
    {
        const unsigned short* src = q + base_qk + (size_t)(s0 + srow) * HDIM + sseg;
        uint4 v0 = *reinterpret_cast<const uint4*>(src);
        uint4 v1 = *reinterpret_cast<const uint4*>(src + 8);
        *reinterpret_cast<uint4*>(&Qs[srow * AT_STRIDE + sseg])     = v0;
        *reinterpret_cast<uint4*>(&Qs[srow * AT_STRIDE + sseg + 8]) = v1;
    }

    // Per-lane softmax state for q-row = s0 + wave*16 + c16 (uniform over quad).
    float m_ = -1.0e30f, l_ = 0.f;
    floatx4 ob[4];
    #pragma unroll
    for (int dt = 0; dt < 4; ++dt) ob[dt] = (floatx4){0.f, 0.f, 0.f, 0.f};

    const int qg = s0 + wave * 16 + c16;   // this lane's q row

    int c0 = s0 - 128; if (c0 < 0) c0 = 0;
    int c1 = s0 + 192; if (c1 > S_LEN) c1 = S_LEN;

    uint4 k0v, k1v, v0v, v1v;
#define LOADKV(CB)                                                                \
    {                                                                             \
        const unsigned short* ksrc = k + base_qk + (size_t)((CB) + srow) * HDIM + sseg; \
        const unsigned short* vsrc = vt + base_vt + (size_t)srow * S_LEN + (CB) + sseg; \
        k0v = *reinterpret_cast<const uint4*>(ksrc);                              \
        k1v = *reinterpret_cast<const uint4*>(ksrc + 8);                          \
        v0v = *reinterpret_cast<const uint4*>(vsrc);                              \
        v1v = *reinterpret_cast<const uint4*>(vsrc + 8);                          \
    }

    LOADKV(c0);

    for (int cb = c0; cb < c1; cb += 64) {
        __syncthreads();      // previous tile's readers done
        *reinterpret_cast<uint4*>(&Ks[srow * AT_STRIDE + sseg])      = k0v;
        *reinterpret_cast<uint4*>(&Ks[srow * AT_STRIDE + sseg + 8])  = k1v;
        *reinterpret_cast<uint4*>(&Vts[srow * AT_STRIDE + sseg])     = v0v;
        *reinterpret_cast<uint4*>(&Vts[srow * AT_STRIDE + sseg + 8]) = v1v;
        __syncthreads();      // K/V tile visible
        if (cb + 64 < c1) LOADKV(cb + 64);   // prefetch next (hides under compute)

        // Swapped QK^T: sc[jt] = K_tile(jt) x Q -> lane holds
        // S[q = qg][j = cb + jt*16 + quad*4 + r], r = 0..3.
        floatx4 sc[4];
        #pragma unroll
        for (int jt = 0; jt < 4; ++jt) sc[jt] = (floatx4){0.f, 0.f, 0.f, 0.f};
        {
            short8 af0 = *reinterpret_cast<const short8*>(
                &Qs[(wave * 16 + c16) * AT_STRIDE + quad * 8]);
            short8 af1 = *reinterpret_cast<const short8*>(
                &Qs[(wave * 16 + c16) * AT_STRIDE + 32 + quad * 8]);
            __builtin_amdgcn_s_setprio(1);
            #pragma unroll
            for (int jt = 0; jt < 4; ++jt) {
                short8 bf0 = *reinterpret_cast<const short8*>(
                    &Ks[(jt * 16 + c16) * AT_STRIDE + quad * 8]);
                short8 bf1 = *reinterpret_cast<const short8*>(
                    &Ks[(jt * 16 + c16) * AT_STRIDE + 32 + quad * 8]);
                sc[jt] = __builtin_amdgcn_mfma_f32_16x16x32_bf16(bf0, af0, sc[jt], 0, 0, 0);
                sc[jt] = __builtin_amdgcn_mfma_f32_16x16x32_bf16(bf1, af1, sc[jt], 0, 0, 0);
            }
            __builtin_amdgcn_s_setprio(0);
        }

        // Lane-local online softmax over the 16 values of this lane's row.
        float rm = -3.0e38f;
        #pragma unroll
        for (int jt = 0; jt < 4; ++jt) {
            #pragma unroll
            for (int r = 0; r < 4; ++r) {
                const int jg = cb + jt * 16 + quad * 4 + r;
                float x = sc[jt][r];
                if (jg < qg - WIN || jg >= qg + WIN) x = -3.0e38f;
                sc[jt][r] = x;
                rm = fmaxf(rm, x);
            }
        }
        rm = fmaxf(rm, __shfl_xor(rm, 16));
        rm = fmaxf(rm, __shfl_xor(rm, 32));

        // T13 defer-max: only advance m_ (and rescale O) when some row's
        // max grew by more than THR=8. exp(m_-mn)==1 exactly otherwise.
        const bool resc = __any(rm - m_ > 8.0f);
        const float mn    = resc ? fmaxf(m_, rm) : m_;
        const float alpha = __expf(m_ - mn);
        float rs = 0.f;
        #pragma unroll
        for (int jt = 0; jt < 4; ++jt) {
            #pragma unroll
            for (int r = 0; r < 4; ++r) {
                const float p = __expf(sc[jt][r] - mn);
                sc[jt][r] = p;
                rs += p;
            }
        }
        rs += __shfl_xor(rs, 16);
        rs += __shfl_xor(rs, 32);
        l_ = l_ * alpha + rs;
        m_ = mn;

        // Broadcast alpha to PV accumulator rows (q = wave*16 + quad*4 + r)
        // — only when a rescale actually happened (wave-uniform branch).
        if (resc) {
            #pragma unroll
            for (int r = 0; r < 4; ++r) {
                const float ar = __shfl(alpha, (lane & 48) | (quad * 4 + r));
                #pragma unroll
                for (int dt = 0; dt < 4; ++dt) ob[dt][r] *= ar;
            }
        }

        // Packed P-store: lane writes its row q=c16, j = jt*16 + quad*4 + 0..3.
        #pragma unroll
        for (int jt = 0; jt < 4; ++jt) {
            uint2 pw;
            pw.x = pk2bf(sc[jt][0], sc[jt][1]);
            pw.y = pk2bf(sc[jt][2], sc[jt][3]);
            *reinterpret_cast<uint2*>(
                &Ps[(wave * 16 + c16) * AT_STRIDE + jt * 16 + quad * 4]) = pw;
        }

        {
            short8 pa0 = *reinterpret_cast<const short8*>(
                &Ps[(wave * 16 + c16) * AT_STRIDE + quad * 8]);
            short8 pa1 = *reinterpret_cast<const short8*>(
                &Ps[(wave * 16 + c16) * AT_STRIDE + 32 + quad * 8]);
            __builtin_amdgcn_s_setprio(1);
            #pragma unroll
            for (int dt = 0; dt < 4; ++dt) {
                short8 bv0 = *reinterpret_cast<const short8*>(
                    &Vts[(dt * 16 + c16) * AT_STRIDE + quad * 8]);
                short8 bv1 = *reinterpret_cast<const short8*>(
                    &Vts[(dt * 16 + c16) * AT_STRIDE + 32 + quad * 8]);
                ob[dt] = __builtin_amdgcn_mfma_f32_16x16x32_bf16(pa0, bv0, ob[dt], 0, 0, 0);
                ob[dt] = __builtin_amdgcn_mfma_f32_16x16x32_bf16(pa1, bv1, ob[dt], 0, 0, 0);
            }
            __builtin_amdgcn_s_setprio(0);
        }
    }
#undef LOADKV

    // Epilogue: O/l -> ctx [S,B,E] bf16 (inv broadcast from softmax lanes).
    const int b = bh >> 4;
    const int h = bh & 15;
    #pragma unroll
    for (int r = 0; r < 4; ++r) {
        const int sg  = s0 + wave * 16 + quad * 4 + r;
        const float lr = __shfl(l_, (lane & 48) | (quad * 4 + r));
        const float inv = 1.0f / lr;
        #pragma unroll
        for (int dt = 0; dt < 4; ++dt) {
            const int d = dt * 16 + c16;
            ctx[((size_t)(sg * BATCH + b) << 10) + (h << 6) + d] = f2bf(ob[dt][r] * inv);
        }
    }
}

// ---------------------------------------------------------------------------
// Output projection (r4 proven form, verbatim). 128x64 tiles -> grid 512
// (2 blocks/CU), BK=64 + 8-way XOR swizzle, 2-barrier single-buffer.
// ctx: [4096,1024] bf16, W: [1024,1024] bf16, out: [S,B,E] f32.
// ---------------------------------------------------------------------------
__global__ __launch_bounds__(256)
void out_gemm_kernel(const unsigned short* __restrict__ ctxb,
                     const unsigned short* __restrict__ wob,
                     const float* __restrict__ bias,
                     float* __restrict__ out)
{
    __shared__ unsigned short As[128 * 64];   // 16 KB
    __shared__ unsigned short Bs[64 * 64];    //  8 KB

    const int bid = blockIdx.x;
    const int bx  = bid >> 5;        // col-tile 0..15 (64 cols)
    const int by  = bid & 31;        // row-panel 0..31 (128 rows, XCD key)

    const int tid  = threadIdx.x;
    const int lane = tid & 63;
    const int wave = tid >> 6;
    const int quad = lane >> 4;
    const int c16  = lane & 15;
    const int wm   = wave * 32;      // wave owns 32 rows x 64 cols

    const int rowBase = by * 128;
    const int colBase = bx * 64;

    const int lrow = lane >> 3;                    // 0..7 within chunk
    const int lseg = (((lane & 7) ^ lrow) << 3);   // permuted k-seg (ushorts)

    floatx4 acc[2][4];
    #pragma unroll
    for (int i = 0; i < 2; ++i)
        #pragma unroll
        for (int j = 0; j < 4; ++j)
            acc[i][j] = (floatx4){0.f, 0.f, 0.f, 0.f};

    const int rxor = c16 & 7;

    for (int k0 = 0; k0 < EMB; k0 += 64) {
        __syncthreads();
        #pragma unroll
        for (int t = 0; t < 4; ++t) {            // A: 16 chunks of 8 rows
            const int c = wave * 4 + t;
            const int row = c * 8 + lrow;
            gl_lds16(ctxb + (size_t)(rowBase + row) * EMB + k0 + lseg, &As[c * 512]);
        }
        #pragma unroll
        for (int t = 0; t < 2; ++t) {            // B: 8 chunks of 8 rows
            const int c = wave * 2 + t;
            const int row = c * 8 + lrow;
            gl_lds16(wob + (size_t)(colBase + row) * EMB + k0 + lseg, &Bs[c * 512]);
        }
        __syncthreads();

        #pragma unroll
        for (int kk = 0; kk < 2; ++kk) {
            const int soff = (((quad + 4 * kk) ^ rxor) << 3);
            short8 af[2], bf[4];
            #pragma unroll
            for (int mi = 0; mi < 2; ++mi)
                af[mi] = *reinterpret_cast<const short8*>(
                    &As[(wm + mi * 16 + c16) * 64 + soff]);
            #pragma unroll
            for (int ni = 0; ni < 4; ++ni)
                bf[ni] = *reinterpret_cast<const short8*>(
                    &Bs[(ni * 16 + c16) * 64 + soff]);

            #pragma unroll
            for (int mi = 0; mi < 2; ++mi)
                #pragma unroll
                for (int ni = 0; ni < 4; ++ni)
                    acc[mi][ni] = __builtin_amdgcn_mfma_f32_16x16x32_bf16(
                        af[mi], bf[ni], acc[mi][ni], 0, 0, 0);
        }
    }

    #pragma unroll
    for (int ni = 0; ni < 4; ++ni) {
        const int n_full = colBase + ni * 16 + c16;
        const float bb = bias[n_full];
        #pragma unroll
        for (int mi = 0; mi < 2; ++mi) {
            #pragma unroll
            for (int r = 0; r < 4; ++r) {
                const int m_g = rowBase + wm + mi * 16 + quad * 4 + r;
                out[(size_t)m_g * EMB + n_full] = acc[mi][ni][r] + bb;
            }
        }
    }
}

// ---------------------------------------------------------------------------
extern "C" void kernel_launch(void* const* d_in, const int* in_sizes, int n_in,
                              void* d_out, int out_size, void* d_ws, size_t ws_size,
                              hipStream_t stream) {
    const float* query = (const float*)d_in[0];
    const float* key   = (const float*)d_in[1];
    const float* value = (const float*)d_in[2];
    const float* in_w  = (const float*)d_in[3];
    const float* in_b  = (const float*)d_in[4];
    const float* out_w = (const float*)d_in[5];
    const float* out_b = (const float*)d_in[6];

    const size_t PLANE = (size_t)BATCH * NHEAD * S_LEN * HDIM;  // 4194304
    unsigned short* xqb = (unsigned short*)d_ws;
    unsigned short* xkb = xqb + PLANE;
    unsigned short* xvb = xkb + PLANE;
    unsigned short* wib = xvb + PLANE;                 // 3*EMB*EMB
    unsigned short* wob = wib + (size_t)3 * EMB * EMB; // EMB*EMB
    unsigned short* qo  = wob + (size_t)EMB * EMB;
    unsigned short* ko  = qo + PLANE;
    unsigned short* vto = ko + PLANE;
    unsigned short* cw  = vto + PLANE;

    convert_kernel<<<8192, 256, 0, stream>>>(query, key, value, in_w, out_w,
                                             xqb, xkb, xvb, wib, wob);

    qkv_gemm_kernel<<<768, 256, 0, stream>>>(xqb, xkb, xvb, wib, in_b, qo, ko, vto);

    attn_mfma_kernel<<<1024, 256, 0, stream>>>(qo, ko, vto, cw);

    out_gemm_kernel<<<512, 256, 0, stream>>>(cw, wob, out_b, (float*)d_out);
}

// Round 10
// 188.058 us; speedup vs baseline: 1.1154x; 1.0061x over previous
//
#include <hip/hip_runtime.h>
#include <hip/hip_bf16.h>

// Problem constants (setup_inputs is fixed)
#define S_LEN 2048
#define BATCH 2
#define EMB   1024
#define NHEAD 16
#define HDIM  64
#define WIN   128

typedef __attribute__((ext_vector_type(8))) short short8;
typedef __attribute__((ext_vector_type(4))) float floatx4;

// Pack two f32 into two RNE-rounded bf16 (lo = a, hi = b).
__device__ __forceinline__ unsigned int pk2bf(float a, float b) {
    unsigned int ua = __builtin_bit_cast(unsigned int, a);
    unsigned int ub = __builtin_bit_cast(unsigned int, b);
    ua += 0x7fffu + ((ua >> 16) & 1u);
    ub += 0x7fffu + ((ub >> 16) & 1u);
    return (ua >> 16) | (ub & 0xffff0000u);
}
__device__ __forceinline__ unsigned short f2bf(float f) {
    unsigned int u = __builtin_bit_cast(unsigned int, f);
    u += 0x7fffu + ((u >> 16) & 1u);
    return (unsigned short)(u >> 16);
}

// Async global->LDS, 16 B per lane. LDS dest = wave-uniform base + lane*16.
__device__ __forceinline__ void gl_lds16(const unsigned short* g, unsigned short* l) {
    __builtin_amdgcn_global_load_lds(
        (const __attribute__((address_space(1))) unsigned int*)g,
        (__attribute__((address_space(3))) unsigned int*)l,
        16, 0, 0);
}

// ---------------------------------------------------------------------------
// Convert pass: f32 -> bf16 for x(q,k,v), in_proj_w, out_proj_w.
// (Fusing x-convert into qkv measured +26 µs regression — keep separate.)
// ---------------------------------------------------------------------------
#define QKV_UNITS 524288          // 4194304/8
#define WI_UNITS  393216          // 3145728/8
#define WO_UNITS  131072          // 1048576/8

__global__ __launch_bounds__(256)
void convert_kernel(const float* __restrict__ xq, const float* __restrict__ xk,
                    const float* __restrict__ xv, const float* __restrict__ wi,
                    const float* __restrict__ wo,
                    unsigned short* __restrict__ xqb, unsigned short* __restrict__ xkb,
                    unsigned short* __restrict__ xvb, unsigned short* __restrict__ wib,
                    unsigned short* __restrict__ wob)
{
    const size_t u = (size_t)blockIdx.x * 256 + threadIdx.x;
    const float* src;
    unsigned short* dst;
    size_t off;
    if (u < 3 * (size_t)QKV_UNITS) {
        const int which = (int)(u / QKV_UNITS);
        off = (u % QKV_UNITS) * 8;
        src = (which == 0) ? xq : (which == 1) ? xk : xv;
        dst = (which == 0) ? xqb : (which == 1) ? xkb : xvb;
    } else if (u < 3 * (size_t)QKV_UNITS + WI_UNITS) {
        off = (u - 3 * (size_t)QKV_UNITS) * 8;
        src = wi; dst = wib;
    } else {
        off = (u - (3 * (size_t)QKV_UNITS + WI_UNITS)) * 8;
        src = wo; dst = wob;
    }
    float4 a = *reinterpret_cast<const float4*>(src + off);
    float4 b = *reinterpret_cast<const float4*>(src + off + 4);
    uint4 p = {pk2bf(a.x, a.y), pk2bf(a.z, a.w), pk2bf(b.x, b.y), pk2bf(b.z, b.w)};
    *reinterpret_cast<uint4*>(dst + off) = p;
}

// ---------------------------------------------------------------------------
// QKV projection, bf16 MFMA GEMM. Best-measured form (45.5 µs) — do NOT
// perturb. Session record for alternatives: dbuf 58.4, BK64+bounce 49.1,
// BK32+bounce 53.5, BK64+scatter 61.8, fused-convert 71, 128x64 tile 66.
// 128x128 tile, BK=32 (16 KB LDS), 2 barriers/K-step, XCD-swizzled 1D grid.
// global_load_lds staging with XOR-swizzled 16B k-segments (4-way).
// Outputs bf16: q,k as [B,H,S,D] (q scaled 0.125), v transposed [B,H,D,S]
// via direct scatter stores.
// ---------------------------------------------------------------------------
__global__ __launch_bounds__(256)
void qkv_gemm_kernel(const unsigned short* __restrict__ xqb,
                     const unsigned short* __restrict__ xkb,
                     const unsigned short* __restrict__ xvb,
                     const unsigned short* __restrict__ wib,   // [3E, E] bf16
                     const float* __restrict__ bias,           // [3E] f32
                     unsigned short* __restrict__ qo,
                     unsigned short* __restrict__ ko,
                     unsigned short* __restrict__ vto)
{
    __shared__ unsigned short As[128 * 32];
    __shared__ unsigned short Bs[128 * 32];

    const int bid  = blockIdx.x;
    const int which = bid >> 8;            // z
    const int bx   = (bid >> 5) & 7;       // col-tile
    const int by   = bid & 31;             // row-panel (XCD key)

    const unsigned short* A = (which == 0) ? xqb : (which == 1) ? xkb : xvb;
    const unsigned short* W = wib + (size_t)which * EMB * EMB;
    const float* bv = bias + which * EMB;
    const float scale = (which == 0) ? 0.125f : 1.0f;

    const int tid  = threadIdx.x;
    const int lane = tid & 63;
    const int wave = tid >> 6;
    const int quad = lane >> 4;
    const int c16  = lane & 15;
    const int wm   = (wave & 1) << 6;
    const int wn   = (wave >> 1) << 6;

    const int rowBase = by * 128;
    const int colBase = bx * 128;

    // Staging: chunk c = 16 rows x 32 ushorts; lane -> (lrow, XOR-perm seg).
    const int lrow = lane >> 2;                        // 0..15 within chunk
    const int lseg = (((lane & 3) ^ (lrow & 3)) << 3); // permuted k-seg (ushorts)

    floatx4 acc[4][4];
    #pragma unroll
    for (int i = 0; i < 4; ++i)
        #pragma unroll
        for (int j = 0; j < 4; ++j)
            acc[i][j] = (floatx4){0.f, 0.f, 0.f, 0.f};

    const int rxor = c16 & 3;   // read-side XOR key (row&3 == c16&3)

    for (int k0 = 0; k0 < EMB; k0 += 32) {
        __syncthreads();
        #pragma unroll
        for (int t = 0; t < 2; ++t) {
            const int c = wave * 2 + t;
            const int row = c * 16 + lrow;
            gl_lds16(A + (size_t)(rowBase + row) * EMB + k0 + lseg, &As[c * 512]);
            gl_lds16(W + (size_t)(colBase + row) * EMB + k0 + lseg, &Bs[c * 512]);
        }
        __syncthreads();

        const int soff = ((quad ^ rxor) << 3);
        short8 af[4], bf[4];
        #pragma unroll
        for (int mi = 0; mi < 4; ++mi)
            af[mi] = *reinterpret_cast<const short8*>(
                &As[(wm + mi * 16 + c16) * 32 + soff]);
        #pragma unroll
        for (int ni = 0; ni < 4; ++ni)
            bf[ni] = *reinterpret_cast<const short8*>(
                &Bs[(wn + ni * 16 + c16) * 32 + soff]);

        #pragma unroll
        for (int mi = 0; mi < 4; ++mi)
            #pragma unroll
            for (int ni = 0; ni < 4; ++ni)
                acc[mi][ni] = __builtin_amdgcn_mfma_f32_16x16x32_bf16(
                    af[mi], bf[ni], acc[mi][ni], 0, 0, 0);
    }

    // Epilogue -> bf16. D[m = quad*4+r][n = c16] per 16x16 tile.
    #pragma unroll
    for (int ni = 0; ni < 4; ++ni) {
        const int n_full = colBase + wn + ni * 16 + c16;   // 0..1023
        const float bb = bv[n_full];
        const int h = n_full >> 6;
        const int d = n_full & 63;
        #pragma unroll
        for (int mi = 0; mi < 4; ++mi) {
            #pragma unroll
            for (int r = 0; r < 4; ++r) {
                const int m_g = rowBase + wm + mi * 16 + quad * 4 + r;
                const int s   = m_g >> 1;      // m = s*B + b
                const int b   = m_g & 1;
                const int bh  = b * NHEAD + h;
                const unsigned short val = f2bf((acc[mi][ni][r] + bb) * scale);
                if (which == 2)
                    vto[((size_t)bh * HDIM + d) * S_LEN + s] = val;
                else if (which == 0)
                    qo[((size_t)bh * S_LEN + s) * HDIM + d] = val;
                else
                    ko[((size_t)bh * S_LEN + s) * HDIM + d] = val;
            }
        }
    }
}

// ---------------------------------------------------------------------------
// MFMA flash attention over the band. 1D grid, XCD-swizzled (bid = sx*32+bh).
// Swapped QK^T (mfma(K,Q)): lane holds the full P-row for q=c16, softmax is
// lane-local (4 shfl_xor total, scalar m/l, packed b64 P-stores).
// s_setprio(1) around MFMA clusters (independent blocks/CU -> T5 regime).
// K/V tiles reg-prefetched one block ahead. ctx out bf16.
// (T13 defer-max measured null here; Q-hoist measured null — both omitted.)
// ---------------------------------------------------------------------------
#define AT_STRIDE 72   // ushorts per LDS row (144B)

__global__ __launch_bounds__(256)
void attn_mfma_kernel(const unsigned short* __restrict__ q,
                      const unsigned short* __restrict__ k,
                      const unsigned short* __restrict__ vt,
                      unsigned short* __restrict__ ctx)
{
    __shared__ unsigned short Qs[64 * AT_STRIDE];
    __shared__ unsigned short Ks[64 * AT_STRIDE];
    __shared__ unsigned short Vts[64 * AT_STRIDE];
    __shared__ unsigned short Ps[64 * AT_STRIDE];

    const int bid = blockIdx.x;
    const int bh  = bid & 31;
    const int s0  = (bid >> 5) * 64;
    const int tid = threadIdx.x;
    const int lane = tid & 63;
    const int wave = tid >> 6;
    const int quad = lane >> 4;
    const int c16  = lane & 15;

    const size_t base_qk = ((size_t)bh * S_LEN) * HDIM;
    const size_t base_vt = ((size_t)bh * HDIM) * S_LEN;

    const int srow = tid >> 2;
    const int sseg = (tid & 3) << 4;
    {
        const unsigned short* src = q + base_qk + (size_t)(s0 + srow) * HDIM + sseg;
        uint4 v0 = *reinterpret_cast<const uint4*>(src);
        uint4 v1 = *reinterpret_cast<const uint4*>(src + 8);
        *reinterpret_cast<uint4*>(&Qs[srow * AT_STRIDE + sseg])     = v0;
        *reinterpret_cast<uint4*>(&Qs[srow * AT_STRIDE + sseg + 8]) = v1;
    }

    // Per-lane softmax state for q-row = s0 + wave*16 + c16 (uniform over quad).
    float m_ = -1.0e30f, l_ = 0.f;
    floatx4 ob[4];
    #pragma unroll
    for (int dt = 0; dt < 4; ++dt) ob[dt] = (floatx4){0.f, 0.f, 0.f, 0.f};

    const int qg = s0 + wave * 16 + c16;   // this lane's q row

    int c0 = s0 - 128; if (c0 < 0) c0 = 0;
    int c1 = s0 + 192; if (c1 > S_LEN) c1 = S_LEN;

    uint4 k0v, k1v, v0v, v1v;
#define LOADKV(CB)                                                                \
    {                                                                             \
        const unsigned short* ksrc = k + base_qk + (size_t)((CB) + srow) * HDIM + sseg; \
        const unsigned short* vsrc = vt + base_vt + (size_t)srow * S_LEN + (CB) + sseg; \
        k0v = *reinterpret_cast<const uint4*>(ksrc);                              \
        k1v = *reinterpret_cast<const uint4*>(ksrc + 8);                          \
        v0v = *reinterpret_cast<const uint4*>(vsrc);                              \
        v1v = *reinterpret_cast<const uint4*>(vsrc + 8);                          \
    }

    LOADKV(c0);

    for (int cb = c0; cb < c1; cb += 64) {
        __syncthreads();      // previous tile's readers done
        *reinterpret_cast<uint4*>(&Ks[srow * AT_STRIDE + sseg])      = k0v;
        *reinterpret_cast<uint4*>(&Ks[srow * AT_STRIDE + sseg + 8])  = k1v;
        *reinterpret_cast<uint4*>(&Vts[srow * AT_STRIDE + sseg])     = v0v;
        *reinterpret_cast<uint4*>(&Vts[srow * AT_STRIDE + sseg + 8]) = v1v;
        __syncthreads();      // K/V tile visible
        if (cb + 64 < c1) LOADKV(cb + 64);   // prefetch next (hides under compute)

        // Swapped QK^T: sc[jt] = K_tile(jt) x Q -> lane holds
        // S[q = qg][j = cb + jt*16 + quad*4 + r], r = 0..3.
        floatx4 sc[4];
        #pragma unroll
        for (int jt = 0; jt < 4; ++jt) sc[jt] = (floatx4){0.f, 0.f, 0.f, 0.f};
        {
            short8 af0 = *reinterpret_cast<const short8*>(
                &Qs[(wave * 16 + c16) * AT_STRIDE + quad * 8]);
            short8 af1 = *reinterpret_cast<const short8*>(
                &Qs[(wave * 16 + c16) * AT_STRIDE + 32 + quad * 8]);
            __builtin_amdgcn_s_setprio(1);
            #pragma unroll
            for (int jt = 0; jt < 4; ++jt) {
                short8 bf0 = *reinterpret_cast<const short8*>(
                    &Ks[(jt * 16 + c16) * AT_STRIDE + quad * 8]);
                short8 bf1 = *reinterpret_cast<const short8*>(
                    &Ks[(jt * 16 + c16) * AT_STRIDE + 32 + quad * 8]);
                sc[jt] = __builtin_amdgcn_mfma_f32_16x16x32_bf16(bf0, af0, sc[jt], 0, 0, 0);
                sc[jt] = __builtin_amdgcn_mfma_f32_16x16x32_bf16(bf1, af1, sc[jt], 0, 0, 0);
            }
            __builtin_amdgcn_s_setprio(0);
        }

        // Lane-local online softmax over the 16 values of this lane's row.
        float rm = -3.0e38f;
        #pragma unroll
        for (int jt = 0; jt < 4; ++jt) {
            #pragma unroll
            for (int r = 0; r < 4; ++r) {
                const int jg = cb + jt * 16 + quad * 4 + r;
                float x = sc[jt][r];
                if (jg < qg - WIN || jg >= qg + WIN) x = -3.0e38f;
                sc[jt][r] = x;
                rm = fmaxf(rm, x);
            }
        }
        rm = fmaxf(rm, __shfl_xor(rm, 16));
        rm = fmaxf(rm, __shfl_xor(rm, 32));
        const float mn    = fmaxf(m_, rm);
        const float alpha = __expf(m_ - mn);
        float rs = 0.f;
        #pragma unroll
        for (int jt = 0; jt < 4; ++jt) {
            #pragma unroll
            for (int r = 0; r < 4; ++r) {
                const float p = __expf(sc[jt][r] - mn);
                sc[jt][r] = p;
                rs += p;
            }
        }
        rs += __shfl_xor(rs, 16);
        rs += __shfl_xor(rs, 32);
        l_ = l_ * alpha + rs;
        m_ = mn;

        // Broadcast alpha to PV accumulator rows (q = wave*16 + quad*4 + r).
        #pragma unroll
        for (int r = 0; r < 4; ++r) {
            const float ar = __shfl(alpha, (lane & 48) | (quad * 4 + r));
            #pragma unroll
            for (int dt = 0; dt < 4; ++dt) ob[dt][r] *= ar;
        }

        // Packed P-store: lane writes its row q=c16, j = jt*16 + quad*4 + 0..3.
        #pragma unroll
        for (int jt = 0; jt < 4; ++jt) {
            uint2 pw;
            pw.x = pk2bf(sc[jt][0], sc[jt][1]);
            pw.y = pk2bf(sc[jt][2], sc[jt][3]);
            *reinterpret_cast<uint2*>(
                &Ps[(wave * 16 + c16) * AT_STRIDE + jt * 16 + quad * 4]) = pw;
        }

        {
            short8 pa0 = *reinterpret_cast<const short8*>(
                &Ps[(wave * 16 + c16) * AT_STRIDE + quad * 8]);
            short8 pa1 = *reinterpret_cast<const short8*>(
                &Ps[(wave * 16 + c16) * AT_STRIDE + 32 + quad * 8]);
            __builtin_amdgcn_s_setprio(1);
            #pragma unroll
            for (int dt = 0; dt < 4; ++dt) {
                short8 bv0 = *reinterpret_cast<const short8*>(
                    &Vts[(dt * 16 + c16) * AT_STRIDE + quad * 8]);
                short8 bv1 = *reinterpret_cast<const short8*>(
                    &Vts[(dt * 16 + c16) * AT_STRIDE + 32 + quad * 8]);
                ob[dt] = __builtin_amdgcn_mfma_f32_16x16x32_bf16(pa0, bv0, ob[dt], 0, 0, 0);
                ob[dt] = __builtin_amdgcn_mfma_f32_16x16x32_bf16(pa1, bv1, ob[dt], 0, 0, 0);
            }
            __builtin_amdgcn_s_setprio(0);
        }
    }
#undef LOADKV

    // Epilogue: O/l -> ctx [S,B,E] bf16 (inv broadcast from softmax lanes).
    const int b = bh >> 4;
    const int h = bh & 15;
    #pragma unroll
    for (int r = 0; r < 4; ++r) {
        const int sg  = s0 + wave * 16 + quad * 4 + r;
        const float lr = __shfl(l_, (lane & 48) | (quad * 4 + r));
        const float inv = 1.0f / lr;
        #pragma unroll
        for (int dt = 0; dt < 4; ++dt) {
            const int d = dt * 16 + c16;
            ctx[((size_t)(sg * BATCH + b) << 10) + (h << 6) + d] = f2bf(ob[dt][r] * inv);
        }
    }
}

// ---------------------------------------------------------------------------
// Output projection. 128x64 tiles -> grid 512 (2 blocks/CU), BK=64 +
// 8-way XOR swizzle, 2-barrier single-buffer. Per-wave 32x64 sub-tile.
// ctx: [4096,1024] bf16, W: [1024,1024] bf16, out: [S,B,E] f32.
// ---------------------------------------------------------------------------
__global__ __launch_bounds__(256)
void out_gemm_kernel(const unsigned short* __restrict__ ctxb,
                     const unsigned short* __restrict__ wob,
                     const float* __restrict__ bias,
                     float* __restrict__ out)
{
    __shared__ unsigned short As[128 * 64];   // 16 KB
    __shared__ unsigned short Bs[64 * 64];    //  8 KB

    const int bid = blockIdx.x;
    const int bx  = bid >> 5;        // col-tile 0..15 (64 cols)
    const int by  = bid & 31;        // row-panel 0..31 (128 rows, XCD key)

    const int tid  = threadIdx.x;
    const int lane = tid & 63;
    const int wave = tid >> 6;
    const int quad = lane >> 4;
    const int c16  = lane & 15;
    const int wm   = wave * 32;      // wave owns 32 rows x 64 cols

    const int rowBase = by * 128;
    const int colBase = bx * 64;

    const int lrow = lane >> 3;                    // 0..7 within chunk
    const int lseg = (((lane & 7) ^ lrow) << 3);   // permuted k-seg (ushorts)

    floatx4 acc[2][4];
    #pragma unroll
    for (int i = 0; i < 2; ++i)
        #pragma unroll
        for (int j = 0; j < 4; ++j)
            acc[i][j] = (floatx4){0.f, 0.f, 0.f, 0.f};

    const int rxor = c16 & 7;

    for (int k0 = 0; k0 < EMB; k0 += 64) {
        __syncthreads();
        #pragma unroll
        for (int t = 0; t < 4; ++t) {            // A: 16 chunks of 8 rows
            const int c = wave * 4 + t;
            const int row = c * 8 + lrow;
            gl_lds16(ctxb + (size_t)(rowBase + row) * EMB + k0 + lseg, &As[c * 512]);
        }
        #pragma unroll
        for (int t = 0; t < 2; ++t) {            // B: 8 chunks of 8 rows
            const int c = wave * 2 + t;
            const int row = c * 8 + lrow;
            gl_lds16(wob + (size_t)(colBase + row) * EMB + k0 + lseg, &Bs[c * 512]);
        }
        __syncthreads();

        #pragma unroll
        for (int kk = 0; kk < 2; ++kk) {
            const int soff = (((quad + 4 * kk) ^ rxor) << 3);
            short8 af[2], bf[4];
            #pragma unroll
            for (int mi = 0; mi < 2; ++mi)
                af[mi] = *reinterpret_cast<const short8*>(
                    &As[(wm + mi * 16 + c16) * 64 + soff]);
            #pragma unroll
            for (int ni = 0; ni < 4; ++ni)
                bf[ni] = *reinterpret_cast<const short8*>(
                    &Bs[(ni * 16 + c16) * 64 + soff]);

            #pragma unroll
            for (int mi = 0; mi < 2; ++mi)
                #pragma unroll
                for (int ni = 0; ni < 4; ++ni)
                    acc[mi][ni] = __builtin_amdgcn_mfma_f32_16x16x32_bf16(
                        af[mi], bf[ni], acc[mi][ni], 0, 0, 0);
        }
    }

    #pragma unroll
    for (int ni = 0; ni < 4; ++ni) {
        const int n_full = colBase + ni * 16 + c16;
        const float bb = bias[n_full];
        #pragma unroll
        for (int mi = 0; mi < 2; ++mi) {
            #pragma unroll
            for (int r = 0; r < 4; ++r) {
                const int m_g = rowBase + wm + mi * 16 + quad * 4 + r;
                out[(size_t)m_g * EMB + n_full] = acc[mi][ni][r] + bb;
            }
        }
    }
}

// ---------------------------------------------------------------------------
extern "C" void kernel_launch(void* const* d_in, const int* in_sizes, int n_in,
                              void* d_out, int out_size, void* d_ws, size_t ws_size,
                              hipStream_t stream) {
    const float* query = (const float*)d_in[0];
    const float* key   = (const float*)d_in[1];
    const float* value = (const float*)d_in[2];
    const float* in_w  = (const float*)d_in[3];
    const float* in_b  = (const float*)d_in[4];
    const float* out_w = (const float*)d_in[5];
    const float* out_b = (const float*)d_in[6];

    const size_t PLANE = (size_t)BATCH * NHEAD * S_LEN * HDIM;  // 4194304
    unsigned short* xqb = (unsigned short*)d_ws;
    unsigned short* xkb = xqb + PLANE;
    unsigned short* xvb = xkb + PLANE;
    unsigned short* wib = xvb + PLANE;                 // 3*EMB*EMB
    unsigned short* wob = wib + (size_t)3 * EMB * EMB; // EMB*EMB
    unsigned short* qo  = wob + (size_t)EMB * EMB;
    unsigned short* ko  = qo + PLANE;
    unsigned short* vto = ko + PLANE;
    unsigned short* cw  = vto + PLANE;

    convert_kernel<<<8192, 256, 0, stream>>>(query, key, value, in_w, out_w,
                                             xqb, xkb, xvb, wib, wob);

    qkv_gemm_kernel<<<768, 256, 0, stream>>>(xqb, xkb, xvb, wib, in_b, qo, ko, vto);

    attn_mfma_kernel<<<1024, 256, 0, stream>>>(qo, ko, vto, cw);

    out_gemm_kernel<<<512, 256, 0, stream>>>(cw, wob, out_b, (float*)d_out);
}